// Round 1
// baseline (102.157 us; speedup 1.0000x reference)
//
#include <hip/hip_runtime.h>
#include <math.h>

#define NS 8192          // sampled points per part (24576/3)
#define NPTS 24576
#define YSPLIT 16
#define YTILE 512        // NS / YSPLIT
#define BX 256
#define XPT 4
#define XB (NS / (BX * XPT))   // 8

// ws float layout:
// [0..3]    accum per combo (combo = part*2 + dir)
// [4..35]   transforms (2 x 16, row-major 4x4)
// [36]      e_kin
// [64..]    float4 pts: tc[2][NS] then cam[2][NS]   (16*NS floats)
// [131136..] partial mins: [4 combos][YSPLIT][NS]   (4*16*8192 floats)

__global__ void prep_kernel(const float* __restrict__ rot_quat,
                            const float* __restrict__ tra,
                            const float* __restrict__ joint_axes,
                            float* __restrict__ ws, float* __restrict__ out) {
    if (threadIdx.x == 0) {
        float T[2][16];
        for (int p = 0; p < 2; ++p) {
            float a = rot_quat[p * 4 + 0], b = rot_quat[p * 4 + 1];
            float c = rot_quat[p * 4 + 2], d = rot_quat[p * 4 + 3];
            float inv = rsqrtf(a * a + b * b + c * c + d * d);
            a *= inv; b *= inv; c *= inv; d *= inv;
            float* t = T[p];
            t[0]  = 1.f - 2.f * c * c - 2.f * d * d;
            t[1]  = 2.f * b * c - 2.f * a * d;
            t[2]  = 2.f * a * c + 2.f * b * d;
            t[3]  = tra[p * 3 + 0];
            t[4]  = 2.f * b * c + 2.f * a * d;
            t[5]  = 1.f - 2.f * b * b - 2.f * d * d;
            t[6]  = 2.f * c * d - 2.f * a * b;
            t[7]  = tra[p * 3 + 1];
            t[8]  = 2.f * b * d - 2.f * a * c;
            t[9]  = 2.f * a * b + 2.f * c * d;
            t[10] = 1.f - 2.f * b * b - 2.f * c * c;
            t[11] = tra[p * 3 + 2];
            t[12] = 0.f; t[13] = 0.f; t[14] = 0.f; t[15] = 1.f;
            for (int k = 0; k < 16; ++k) {
                ws[4 + p * 16 + k] = t[k];
                out[2 + p * 16 + k] = t[k];
            }
        }
        // e_kin: diff = T0 @ J0^T - T1 @ J1^T  (4x2), Frobenius norm
        float ss = 0.f;
        for (int i = 0; i < 4; ++i) {
            for (int j = 0; j < 2; ++j) {
                float d0 = 0.f, d1 = 0.f;
                for (int k = 0; k < 4; ++k) {
                    d0 += T[0][i * 4 + k] * joint_axes[0 * 8 + j * 4 + k];
                    d1 += T[1][i * 4 + k] * joint_axes[1 * 8 + j * 4 + k];
                }
                float df = d0 - d1;
                ss += df * df;
            }
        }
        float nrm = sqrtf(ss);
        float ek = 1.f / (1.f + expf(5.f * nrm));
        ws[36] = ek;
        out[1] = ek;
        ws[0] = 0.f; ws[1] = 0.f; ws[2] = 0.f; ws[3] = 0.f;
    }
}

__global__ void pack_kernel(const float* __restrict__ cam_pts,
                            const float* __restrict__ cad_pts,
                            const float* __restrict__ ws,
                            float4* __restrict__ pts) {
    int gid = blockIdx.x * blockDim.x + threadIdx.x;
    if (gid >= 2 * NS) return;
    int p = gid >> 13;          // / NS
    int i = gid & (NS - 1);
    const float* T = ws + 4 + p * 16;
    int base = p * NPTS * 3 + i * 9;   // sample step 3, 3 floats each
    float x = cad_pts[base], y = cad_pts[base + 1], z = cad_pts[base + 2];
    float q0 = T[0] * x + T[1] * y + T[2]  * z + T[3];
    float q1 = T[4] * x + T[5] * y + T[6]  * z + T[7];
    float q2 = T[8] * x + T[9] * y + T[10] * z + T[11];
    pts[p * NS + i] = make_float4(q0, q1, q2, q0 * q0 + q1 * q1 + q2 * q2);
    float cx = cam_pts[base], cy = cam_pts[base + 1], cz = cam_pts[base + 2];
    pts[2 * NS + p * NS + i] = make_float4(cx, cy, cz, cx * cx + cy * cy + cz * cz);
}

__global__ __launch_bounds__(BX) void chamfer_kernel(const float4* __restrict__ pts,
                                                     float* __restrict__ partial) {
    int combo = blockIdx.y;           // p*2 + dir
    int p   = combo >> 1;
    int dir = combo & 1;
    const float4* X = pts + (dir == 0 ? p * NS : 2 * NS + p * NS);
    const float4* Y = pts + (dir == 0 ? 2 * NS + p * NS : p * NS);
    int ys = blockIdx.z;
    int xb = blockIdx.x;

    __shared__ float4 sy[YTILE];

    int xbase = xb * (BX * XPT) + threadIdx.x;
    float m0[XPT], m1[XPT], m2[XPT], s[XPT], dmin[XPT];
#pragma unroll
    for (int k = 0; k < XPT; ++k) {
        float4 v = X[xbase + k * BX];
        m0[k] = -2.f * v.x;
        m1[k] = -2.f * v.y;
        m2[k] = -2.f * v.z;
        s[k]  = v.w;
        dmin[k] = 3.4e38f;
    }

    int ybase = ys * YTILE;
    sy[threadIdx.x]       = Y[ybase + threadIdx.x];
    sy[threadIdx.x + BX]  = Y[ybase + BX + threadIdx.x];
    __syncthreads();

#pragma unroll 4
    for (int j = 0; j < YTILE; ++j) {
        float4 y = sy[j];
#pragma unroll
        for (int k = 0; k < XPT; ++k) {
            float d = s[k] + y.w;
            d = fmaf(m0[k], y.x, d);
            d = fmaf(m1[k], y.y, d);
            d = fmaf(m2[k], y.z, d);
            dmin[k] = fminf(dmin[k], d);
        }
    }

#pragma unroll
    for (int k = 0; k < XPT; ++k) {
        partial[combo * (YSPLIT * NS) + ys * NS + xbase + k * BX] = dmin[k];
    }
}

__global__ void reduce_kernel(const float* __restrict__ partial,
                              float* __restrict__ accum) {
    int combo = blockIdx.y;
    int x = blockIdx.x * 256 + threadIdx.x;
    const float* p = partial + combo * (YSPLIT * NS) + x;
    float m = p[0];
#pragma unroll
    for (int ysi = 1; ysi < YSPLIT; ++ysi) m = fminf(m, p[ysi * NS]);
    float d = sqrtf(fmaxf(m, 0.f));
#pragma unroll
    for (int off = 32; off > 0; off >>= 1) d += __shfl_down(d, off, 64);
    __shared__ float sm[4];
    int wid = threadIdx.x >> 6;
    if ((threadIdx.x & 63) == 0) sm[wid] = d;
    __syncthreads();
    if (threadIdx.x == 0) {
        float sum = sm[0] + sm[1] + sm[2] + sm[3];
        atomicAdd(&accum[combo], sum);
    }
}

__global__ void finalize_kernel(const float* __restrict__ ws,
                                const float* __restrict__ pw,
                                float* __restrict__ out) {
    if (threadIdx.x == 0) {
        float e0 = (ws[0] + ws[1]) * (1.f / NS);
        float e1 = (ws[2] + ws[3]) * (1.f / NS);
        float e_geo = pw[0] * e0 + pw[1] * e1;
        out[0] = e_geo + pw[2] * ws[36];
    }
}

extern "C" void kernel_launch(void* const* d_in, const int* in_sizes, int n_in,
                              void* d_out, int out_size, void* d_ws, size_t ws_size,
                              hipStream_t stream) {
    const float* cam = (const float*)d_in[0];
    const float* cad = (const float*)d_in[1];
    const float* pw  = (const float*)d_in[2];
    const float* rq  = (const float*)d_in[3];
    const float* tr  = (const float*)d_in[4];
    const float* ja  = (const float*)d_in[5];
    float* out = (float*)d_out;
    float* ws  = (float*)d_ws;
    float4* pts = (float4*)(ws + 64);
    float* partial = ws + 64 + 16 * NS;   // after 4*NS float4s

    prep_kernel<<<1, 64, 0, stream>>>(rq, tr, ja, ws, out);
    pack_kernel<<<(2 * NS) / 256, 256, 0, stream>>>(cam, cad, ws, pts);
    dim3 cg(XB, 4, YSPLIT);
    chamfer_kernel<<<cg, BX, 0, stream>>>(pts, partial);
    reduce_kernel<<<dim3(NS / 256, 4), 256, 0, stream>>>(partial, ws);
    finalize_kernel<<<1, 64, 0, stream>>>(ws, pw, out);
}